// Round 1
// baseline (1289.512 us; speedup 1.0000x reference)
//
#include <hip/hip_runtime.h>
#include <math.h>

#define CCH 128
#define BSZ 32
#define KN 4

// ---------------- Kernel A: global average pool ----------------
// grid = B*C blocks, 256 threads. Each block reduces 4096 contiguous floats.
__global__ __launch_bounds__(256) void pool_kernel(const float* __restrict__ x,
                                                   float* __restrict__ pooled) {
    int blk = blockIdx.x;                 // b*C + c
    const float4* x4 = (const float4*)(x + (size_t)blk * 4096);
    int t = threadIdx.x;
    float s = 0.f;
#pragma unroll
    for (int j = 0; j < 4; ++j) {
        float4 v = x4[j * 256 + t];
        s += v.x + v.y + v.z + v.w;
    }
#pragma unroll
    for (int off = 32; off; off >>= 1) s += __shfl_xor(s, off, 64);
    __shared__ float red[4];
    if ((t & 63) == 0) red[t >> 6] = s;
    __syncthreads();
    if (t == 0) {
        float tot = red[0] + red[1] + red[2] + red[3];
        pooled[blk] = tot * (1.0f / 4096.0f);
    }
}

// ---------------- Kernel B: routing coefficients ----------------
// 1 block, 128 threads: thread t -> (b = t>>2, k = t&3)
__global__ __launch_bounds__(128) void coeff_kernel(const float* __restrict__ pooled,
                                                    const float* __restrict__ fc_w,
                                                    const float* __restrict__ fc_b,
                                                    float* __restrict__ coeffs) {
    int t = threadIdx.x;
    int b = t >> 2, k = t & 3;
    float dot = fc_b[k];
    for (int c = 0; c < CCH; ++c) dot += pooled[b * CCH + c] * fc_w[k * CCH + c];
    float s = 1.0f / (1.0f + expf(-dot));
    // softmax over the 4 lanes sharing b (lanes 4b..4b+3, within one wave)
    float m = s;
    m = fmaxf(m, __shfl_xor(m, 1, 64));
    m = fmaxf(m, __shfl_xor(m, 2, 64));
    float e = expf(s - m);
    float sum = e;
    sum += __shfl_xor(sum, 1, 64);
    sum += __shfl_xor(sum, 2, 64);
    coeffs[t] = e / sum;
}

// ---------------- Kernel C: dynamic conv ----------------
// grid = 32 b * 16 co-blocks * 4 spatial tiles = 2048 blocks, 256 threads.
// Block: 8 c_out, 32x32 spatial tile; thread: 2x2 pixel quad -> 8*4 acc.
// Loop ci in chunks of 4: stage 4x34x34 x-halo tile + on-the-fly mixed
// weights (padded to 12 floats for b128 broadcast reads) in LDS.
__global__ __launch_bounds__(256) void conv_kernel(const float* __restrict__ x,
                                                   const float* __restrict__ kernels,
                                                   const float* __restrict__ coeffs,
                                                   float* __restrict__ out) {
    __shared__ float xs[4 * 34 * 34];   // 4624 floats
    __shared__ float wl[8 * 4 * 12];    // mixed weights, padded

    int blk = blockIdx.x;
    int tx = blk & 1, ty = (blk >> 1) & 1, cb = (blk >> 2) & 15, b = blk >> 6;
    int co0 = cb * 8;
    int t = threadIdx.x;
    int qx = t & 15, qy = t >> 4;

    float cf0 = coeffs[b * 4 + 0];
    float cf1 = coeffs[b * 4 + 1];
    float cf2 = coeffs[b * 4 + 2];
    float cf3 = coeffs[b * 4 + 3];

    float acc[8][4];
#pragma unroll
    for (int i = 0; i < 8; ++i)
#pragma unroll
        for (int j = 0; j < 4; ++j) acc[i][j] = 0.f;

    const int oy0 = ty * 32, ox0 = tx * 32;
    const size_t kstride = (size_t)KN == 0 ? 0 : (size_t)CCH * CCH * 9;

    for (int ci0 = 0; ci0 < CCH; ci0 += 4) {
        __syncthreads();
        // ---- stage x tile (4 channels, 34x34 with zero halo) ----
        for (int i = t; i < 4 * 1156; i += 256) {
            int ci = i / 1156;
            int rem = i - ci * 1156;
            int r = rem / 34;
            int cc = rem - r * 34;
            int gy = oy0 - 1 + r;
            int gx = ox0 - 1 + cc;
            float v = 0.f;
            if ((unsigned)gy < 64u && (unsigned)gx < 64u)
                v = x[(((size_t)b * CCH + ci0 + ci) * 64 + gy) * 64 + gx];
            xs[i] = v;
        }
        // ---- stage mixed weights: wl[co][ci][r] = sum_k cf[k]*kernels[k,co,ci,r]
        for (int i = t; i < 8 * 4 * 9; i += 256) {
            int co = i / 36;
            int rem = i - co * 36;
            int ci = rem / 9;
            int r = rem - ci * 9;
            size_t base = (((size_t)(co0 + co)) * CCH + (ci0 + ci)) * 9 + r;
            float wv = cf0 * kernels[base]
                     + cf1 * kernels[base + kstride]
                     + cf2 * kernels[base + 2 * kstride]
                     + cf3 * kernels[base + 3 * kstride];
            wl[(co * 4 + ci) * 12 + r] = wv;
        }
        __syncthreads();
        // ---- compute ----
#pragma unroll
        for (int ci = 0; ci < 4; ++ci) {
            float xv[4][4];
            int base = ci * 1156 + (qy * 2) * 34 + qx * 2;
#pragma unroll
            for (int rr = 0; rr < 4; ++rr) {
                float2 a = *(const float2*)&xs[base + rr * 34];
                float2 c2 = *(const float2*)&xs[base + rr * 34 + 2];
                xv[rr][0] = a.x; xv[rr][1] = a.y; xv[rr][2] = c2.x; xv[rr][3] = c2.y;
            }
#pragma unroll
            for (int co = 0; co < 8; ++co) {
                const float* wp = &wl[(co * 4 + ci) * 12];
                float4 w0 = *(const float4*)wp;
                float4 w1 = *(const float4*)(wp + 4);
                float w8 = wp[8];
                float w[9] = {w0.x, w0.y, w0.z, w0.w, w1.x, w1.y, w1.z, w1.w, w8};
#pragma unroll
                for (int dy = 0; dy < 3; ++dy)
#pragma unroll
                    for (int dx = 0; dx < 3; ++dx) {
                        float wt = w[dy * 3 + dx];
                        acc[co][0] = fmaf(wt, xv[dy][dx],         acc[co][0]);
                        acc[co][1] = fmaf(wt, xv[dy][dx + 1],     acc[co][1]);
                        acc[co][2] = fmaf(wt, xv[dy + 1][dx],     acc[co][2]);
                        acc[co][3] = fmaf(wt, xv[dy + 1][dx + 1], acc[co][3]);
                    }
            }
        }
    }
    // ---- epilogue: coalesced float2 stores ----
    int y0 = oy0 + qy * 2, x0 = ox0 + qx * 2;
#pragma unroll
    for (int co = 0; co < 8; ++co) {
        size_t o = (((size_t)b * CCH + co0 + co) * 64 + y0) * 64 + x0;
        *(float2*)&out[o]      = make_float2(acc[co][0], acc[co][1]);
        *(float2*)&out[o + 64] = make_float2(acc[co][2], acc[co][3]);
    }
}

extern "C" void kernel_launch(void* const* d_in, const int* in_sizes, int n_in,
                              void* d_out, int out_size, void* d_ws, size_t ws_size,
                              hipStream_t stream) {
    const float* x       = (const float*)d_in[0];   // [32,128,64,64]
    const float* kernels = (const float*)d_in[1];   // [4,128,128,3,3]
    const float* fc_w    = (const float*)d_in[2];   // [4,128]
    const float* fc_b    = (const float*)d_in[3];   // [4]
    float* out = (float*)d_out;

    float* pooled = (float*)d_ws;            // 4096 floats
    float* coeffs = pooled + BSZ * CCH;      // 128 floats

    pool_kernel<<<BSZ * CCH, 256, 0, stream>>>(x, pooled);
    coeff_kernel<<<1, 128, 0, stream>>>(pooled, fc_w, fc_b, coeffs);
    conv_kernel<<<2048, 256, 0, stream>>>(x, kernels, coeffs, out);
}

// Round 2
// 124.716 us; speedup vs baseline: 10.3396x; 10.3396x over previous
//
#include <hip/hip_runtime.h>
#include <math.h>

typedef __attribute__((ext_vector_type(8))) short s16x8;
typedef __attribute__((ext_vector_type(4))) float f32x4;

#define CCH 128
#define BSZ 32

// fp32 -> bf16 round-to-nearest-even (no NaN handling; inputs are normal)
static __device__ inline unsigned short f2bf(float f) {
    unsigned u = __float_as_uint(f);
    unsigned r = (u + 0x7FFFu + ((u >> 16) & 1u)) >> 16;
    return (unsigned short)r;
}

// ---------------- Kernel A: global average pool ----------------
__global__ __launch_bounds__(256) void pool_kernel(const float* __restrict__ x,
                                                   float* __restrict__ pooled) {
    int blk = blockIdx.x;                 // b*C + c
    const float4* x4 = (const float4*)(x + (size_t)blk * 4096);
    int t = threadIdx.x;
    float s = 0.f;
#pragma unroll
    for (int j = 0; j < 4; ++j) {
        float4 v = x4[j * 256 + t];
        s += v.x + v.y + v.z + v.w;
    }
#pragma unroll
    for (int off = 32; off; off >>= 1) s += __shfl_xor(s, off, 64);
    __shared__ float red[4];
    if ((t & 63) == 0) red[t >> 6] = s;
    __syncthreads();
    if (t == 0) {
        float tot = red[0] + red[1] + red[2] + red[3];
        pooled[blk] = tot * (1.0f / 4096.0f);
    }
}

// ---------------- Kernel B: routing coefficients ----------------
__global__ __launch_bounds__(128) void coeff_kernel(const float* __restrict__ pooled,
                                                    const float* __restrict__ fc_w,
                                                    const float* __restrict__ fc_b,
                                                    float* __restrict__ coeffs) {
    int t = threadIdx.x;
    int b = t >> 2, k = t & 3;
    float dot = fc_b[k];
    for (int c = 0; c < CCH; ++c) dot += pooled[b * CCH + c] * fc_w[k * CCH + c];
    float s = 1.0f / (1.0f + expf(-dot));
    float m = s;
    m = fmaxf(m, __shfl_xor(m, 1, 64));
    m = fmaxf(m, __shfl_xor(m, 2, 64));
    float e = expf(s - m);
    float sum = e;
    sum += __shfl_xor(sum, 1, 64);
    sum += __shfl_xor(sum, 2, 64);
    coeffs[t] = e / sum;
}

// ---------------- Kernel W: mix weights -> bf16, padded layout ----------------
// wmix[b][cc(4)][dy(3)][dx(3)][co(128)][ci 32 padded to 40] bf16
// per-b stride 184320, per-cc 46080, per-dy 15360, per-dx 5120, per-co 40.
__global__ __launch_bounds__(256) void mix_kernel(const float* __restrict__ kernels,
                                                  const float* __restrict__ coeffs,
                                                  unsigned short* __restrict__ wmix) {
    int idx = blockIdx.x * 256 + threadIdx.x;   // < 589824
    int c8 = idx & 3;            // which octet of ci (0..3)
    int r = idx >> 2;
    int co = r & 127; r >>= 7;   // r < 1152 = b(32)*cc(4)*dy(3)*dx(3)
    int dx = r % 3; int r2 = r / 3;
    int dy = r2 % 3; r2 /= 3;
    int cc = r2 & 3; int b = r2 >> 2;

    float cf0 = coeffs[b * 4 + 0];
    float cf1 = coeffs[b * 4 + 1];
    float cf2 = coeffs[b * 4 + 2];
    float cf3 = coeffs[b * 4 + 3];

    const int KSTR = 128 * 128 * 9;   // k-bank stride in kernels
    unsigned short vals[8];
#pragma unroll
    for (int i = 0; i < 8; ++i) {
        int ci = cc * 32 + c8 * 8 + i;
        const float* kp = kernels + ((size_t)co * CCH + ci) * 9 + dy * 3 + dx;
        float s = cf0 * kp[0] + cf1 * kp[KSTR] + cf2 * kp[2 * KSTR] + cf3 * kp[3 * KSTR];
        vals[i] = f2bf(s);
    }
    size_t o = ((size_t)((((b * 4 + cc) * 3 + dy) * 3 + dx) * 128 + co)) * 40 + c8 * 8;
    *(s16x8*)&wmix[o] = *(const s16x8*)vals;
}

// ---------------- Kernel C: MFMA implicit-GEMM dynamic conv ----------------
// grid = 32 b * 16 y-tiles(4 rows) = 512 blocks, 512 threads (8 waves: 2 co x 4 px-row)
// per block: 128 co x 256 px; K loop: 4 chunks of 32 ci, dy-staged weights (3 dx).
__global__ __launch_bounds__(512, 4) void conv_kernel(const float* __restrict__ x,
                                                      const unsigned short* __restrict__ wmix,
                                                      float* __restrict__ out) {
    __shared__ unsigned short xs[6 * 66 * 40];   // [row][col(-1..64)][ci pad40]  31680 B
    __shared__ unsigned short wl[1920 * 8];      // [dx(3)][co(128)][ci pad40]    30720 B

    int blk = blockIdx.x;
    int ytile = blk & 15, b = blk >> 4;
    int y0 = ytile * 4;
    int t = threadIdx.x;
    int l = t & 63, w = t >> 6;
    int wr = w >> 2, wc = w & 3;      // wr: which 64-co half; wc: pixel row in tile
    int l15 = l & 15, g = l >> 4;

    // zero halo columns (col 0 and 65) once; first barrier orders it
    if (t < 240) {
        int cpart = t % 20;
        int colsel = (t / 20) & 1;
        int row = t / 40;
        int col = colsel * 65;
        *(unsigned*)&xs[(row * 66 + col) * 40 + cpart * 2] = 0u;
    }

    f32x4 acc[4][4] = {};

    const unsigned short* wb = wmix + (size_t)b * 184320;

    for (int cc = 0; cc < 4; ++cc) {
        __syncthreads();
        // ---- stage X chunk: 32 ci, rows y0-1..y0+4, cols 0..63 (+1 shift in LDS) ----
        {
            int col16 = l15, cplo = g;
            for (int it = w; it < 96; it += 8) {
                int row = it >> 4;              // 0..5
                int colhi = (it >> 2) & 3;      // 0..3
                int cphi = it & 3;              // 0..3
                int cp = cphi * 4 + cplo;       // ci pair 0..15
                int gx = colhi * 16 + col16;    // 0..63
                int gy = y0 + row - 1;
                float v0 = 0.f, v1 = 0.f;
                if ((unsigned)gy < 64u) {
                    const float* xp = x + (((size_t)b * CCH + cc * 32 + cp * 2) * 64 + gy) * 64 + gx;
                    v0 = xp[0];
                    v1 = xp[4096];
                }
                unsigned pk = (unsigned)f2bf(v0) | ((unsigned)f2bf(v1) << 16);
                *(unsigned*)&xs[(row * 66 + gx + 1) * 40 + cp * 2] = pk;
            }
        }
        for (int dy = 0; dy < 3; ++dy) {
            __syncthreads();   // previous compute done before wl overwrite (also covers X/halo)
            // ---- stage W (cc,dy): linear 30720 B copy (layout already padded) ----
            const unsigned short* wsrc = wb + ((size_t)cc * 3 + dy) * 15360;
            for (int s = t; s < 1920; s += 512) {
                *(s16x8*)&wl[s * 8] = *(const s16x8*)&wsrc[s * 8];
            }
            __syncthreads();
            // ---- compute ----
            int xrow = wc + dy;
#pragma unroll
            for (int dx = 0; dx < 3; ++dx) {
                s16x8 a[4];
#pragma unroll
                for (int mt = 0; mt < 4; ++mt)
                    a[mt] = *(const s16x8*)&wl[(dx * 128 + wr * 64 + mt * 16 + l15) * 40 + g * 8];
#pragma unroll
                for (int nt = 0; nt < 4; ++nt) {
                    s16x8 bf = *(const s16x8*)&xs[(xrow * 66 + nt * 16 + l15 + dx) * 40 + g * 8];
#pragma unroll
                    for (int mt = 0; mt < 4; ++mt)
                        acc[mt][nt] = __builtin_amdgcn_mfma_f32_16x16x32_bf16(
                            a[mt], bf, acc[mt][nt], 0, 0, 0);
                }
            }
        }
    }
    // ---- epilogue: D row = co = (l>>4)*4+j, col = px = l&15 ----
    int gy_out = y0 + wc;
#pragma unroll
    for (int mt = 0; mt < 4; ++mt) {
#pragma unroll
        for (int nt = 0; nt < 4; ++nt) {
            int gx_out = nt * 16 + l15;
#pragma unroll
            for (int j = 0; j < 4; ++j) {
                int co = wr * 64 + mt * 16 + g * 4 + j;
                out[(((size_t)b * CCH + co) * 64 + gy_out) * 64 + gx_out] = acc[mt][nt][j];
            }
        }
    }
}

extern "C" void kernel_launch(void* const* d_in, const int* in_sizes, int n_in,
                              void* d_out, int out_size, void* d_ws, size_t ws_size,
                              hipStream_t stream) {
    const float* x       = (const float*)d_in[0];   // [32,128,64,64]
    const float* kernels = (const float*)d_in[1];   // [4,128,128,3,3]
    const float* fc_w    = (const float*)d_in[2];   // [4,128]
    const float* fc_b    = (const float*)d_in[3];   // [4]
    float* out = (float*)d_out;

    float* pooled = (float*)d_ws;                        // 4096 f
    float* coeffs = pooled + BSZ * CCH;                  // 128 f
    unsigned short* wmix = (unsigned short*)((char*)d_ws + 32768);  // 11.8 MB bf16

    pool_kernel<<<BSZ * CCH, 256, 0, stream>>>(x, pooled);
    coeff_kernel<<<1, 128, 0, stream>>>(pooled, fc_w, fc_b, coeffs);
    mix_kernel<<<2304, 256, 0, stream>>>(kernels, coeffs, wmix);
    conv_kernel<<<512, 512, 0, stream>>>(x, wmix, out);
}